// Round 9
// baseline (362.636 us; speedup 1.0000x reference)
//
#include <hip/hip_runtime.h>
#include <type_traits>
#include <cmath>
#include <cstdint>

#define NRAYS     262144
#define HASHMAP   524288
#define DIM       256
#define NMID      6
#define MBLK      64
#define ALPHA     512.0f          // power-of-2 activation scale: lifts h (~1e-4) out of
#define INV_ALPHA (1.0f / 512.0f) // fp16 subnormal range; exact, removed at output.

typedef _Float16 half8 __attribute__((ext_vector_type(8)));
typedef _Float16 half2 __attribute__((ext_vector_type(2)));
typedef float  floatx4 __attribute__((ext_vector_type(4)));
typedef __attribute__((address_space(3))) uint32_t lds_u32_t;
typedef __attribute__((address_space(1))) uint32_t gbl_u32_t;

// ws layout (_Float16 elements) — fp16 weights, single product per MFMA:
//   [0, 8192):        W_in  fragments [nc:16][lane:64][j:8]  (K padded 16->32 with zeros)
//   [8192, 401408):   W_mid fragments [L:6][kc:8][nc:16][lane:64][j:8]
//
// SESSION INVARIANT (R10/R11/R14): the ~2-7e-6 few-elements-wrong miscompile
// class fires on ANY novel MFMA-loop register shape. The ONLY trusted
// micro-structure is R13's per-wave loop: b[4]+a[4] input regs, acc[4][4]
// floatx4, one setprio cluster, nl=4, unroll(disable) on kc. NEVER deviate.
//
// R12 (pass, 326us): strength-reduced A addressing + s_setprio.
// R13 (pass, 222us): strength-reduced epilogue addressing.
// R15 (pass, 238us): MBLK=128 neutral-negative — weights already L2-resident.
// R16 (pass, 225us): bias into MFMA C-in — NEUTRAL. Key counter insight:
//   VALUBusy ~= MfmaUtil (43.6 == 43.6) => VALUBusy INCLUDES MFMA on CDNA;
//   plain VALU ~ 0. The other 56% is load-latency stall: per kc the 4 global
//   b-loads (L2 ~250cyc, WAR-serialized on the frozen b[4]) gate 16 MFMA.
// R17: global_load_lds weight staging. b-loads become DMA global->LDS issued
//   for kc+1 right after kc's lgkm drain (wave-private 4KB buffer — NO barrier),
//   hidden under kc's MFMA cluster. Loop reads b[4] via ds_read_b128 from the
//   staged copy — same registers, same bytes, bit-identical arithmetic
//   (absmax must stay exactly 1.192093e-07). LDS 48KB -> 3 blocks/CU.
#define WIN_ELEMS   8192
#define WL_ELEMS    65536
#define WKC_ELEMS   8192
#define WNC_ELEMS   512

// Gray-coded XOR swizzle (R4, frozen — conflict counter insensitive to choice).
__device__ __forceinline__ int sw_idx(int r, int k) {
  int s = (r ^ (r >> 1)) & 7;
  return (r << 8) + ((((k >> 3) ^ s) << 3) | (k & 7));
}

__global__ __launch_bounds__(256) void prep_weights(
    const float* __restrict__ W_in, const float* __restrict__ W_mid,
    _Float16* __restrict__ wsh)
{
  int tid = blockIdx.x * 256 + threadIdx.x;
  int pos = tid & 511;             // lane*8 + j
  int lane = pos >> 3, j = pos & 7;
  int kk = ((lane >> 4) << 3) + j; // quad*8 + j, 0..31
  if (tid < WIN_ELEMS) {
    int nc = tid >> 9;
    int n = (nc << 4) + (lane & 15);
    float v = (kk < 16) ? W_in[kk * DIM + n] : 0.f;
    wsh[nc * WNC_ELEMS + pos] = (_Float16)v;
  } else if (tid < WIN_ELEMS + 6 * WL_ELEMS) {
    int u = tid - WIN_ELEMS;
    int fid = u >> 9;              // 0..767
    int L   = fid >> 7;
    int rem = fid & 127;
    int kc  = rem >> 4;
    int nc  = rem & 15;
    int k = (kc << 5) + kk;
    int n = (nc << 4) + (lane & 15);
    float v = W_mid[L * (DIM * DIM) + k * DIM + n];
    wsh[WIN_ELEMS + L * WL_ELEMS + kc * WKC_ELEMS + nc * WNC_ELEMS + pos] = (_Float16)v;
  }
}

// (256,4): the second arg is the REGISTER-CAP invariant (128 = arch 64 + acc
// 64); LDS (48KB) independently limits residency to 3 blocks/CU (12 waves).
// With staged weights each wave's duty cycle ~67% -> 3 waves/SIMD saturate
// the matrix pipe.
__global__ __launch_bounds__(256, 4) void mlp_fused(
    const float* __restrict__ x,
    const float* __restrict__ table1,
    const float* __restrict__ table2,
    const _Float16* __restrict__ wsh,
    const float* __restrict__ b_in,
    const float* __restrict__ b_mid,
    const float* __restrict__ W_out,
    const float* __restrict__ b_out,
    float* __restrict__ out,
    int res0, int res1, int res2, int res3)
{
  __shared__ __align__(16) _Float16 hs[MBLK * 256];   // 32KB activations, swizzled
  __shared__ __align__(16) _Float16 wstage[4 * 2048]; // 16KB: per-wave 4KB weight stage

  const int tid  = threadIdx.x;
  const int lane = tid & 63;
  const int wave = tid >> 6;
  const int col  = lane & 15;
  const int quad = lane >> 4;
  const int rbase = blockIdx.x * MBLK;

  // R17: stage the 4 b-fragments (4KB) of one kc into this wave's private
  // region of wstage via direct global->LDS DMA (no VGPR round-trip).
  // src fragment layout is [nc][lane][j]: lane-contiguous 16B — exactly the
  // wave-uniform-base + lane*16 pattern global_load_lds requires.
  auto stage4 = [&](const _Float16* __restrict__ wk) {
    const _Float16* src = wk + wave * 2048 + lane * 8;
    _Float16* dst = &wstage[wave * 2048];
    #pragma unroll
    for (int nl = 0; nl < 4; ++nl)
      __builtin_amdgcn_global_load_lds((gbl_u32_t*)(src + nl * WNC_ELEMS),
                                       (lds_u32_t*)(dst + nl * WNC_ELEMS),
                                       16, 0, 0);
  };

  // ---------------- hash-grid encode: 512 (ray,enc,level) tasks, 2 per thread ----------------
  #pragma unroll
  for (int i = 0; i < 2; ++i) {
    int task = tid + (i << 8);
    int r   = task & 63;
    int el  = task >> 6;           // 0..7
    int enc = el >> 2, lev = el & 3;
    const float* xp = x + (size_t)(rbase + r) * 4 + enc * 2;
    float px = xp[0], py = xp[1];
    int res = (lev == 0) ? res0 : (lev == 1) ? res1 : (lev == 2) ? res2 : res3;
    float fres = (float)res;
    float xf = px * fres, yf = py * fres;
    float xi = floorf(xf), yi = floorf(yf);
    float fx = xf - xi,  fy = yf - yi;
    uint32_t ix = (uint32_t)xi, iy = (uint32_t)yi;
    const float2* tab = (const float2*)(enc ? table2 : table1) + (size_t)lev * HASHMAP;
    float f0 = 0.f, f1 = 0.f;
    #pragma unroll
    for (int c = 0; c < 4; ++c) {                    // corners (0,0),(0,1),(1,0),(1,1)
      uint32_t c0 = (uint32_t)(c >> 1), c1 = (uint32_t)(c & 1);
      uint32_t h = ((ix + c0) ^ ((iy + c1) * 2654435761u)) & (uint32_t)(HASHMAP - 1);
      float2 v = tab[h];
      float w = (c0 ? fx : 1.f - fx) * (c1 ? fy : 1.f - fy);
      f0 += w * v.x;
      f1 += w * v.y;
    }
    int cb = enc * 8 + lev * 2;                      // emb column (concat: enc-major, level, feat)
    half2 hp = {(_Float16)(f0 * ALPHA), (_Float16)(f1 * ALPHA)};
    *(half2*)&hs[sw_idx(r, cb)] = hp;
  }
  // zero K-pad columns 16..31 for the first (K=32) MFMA
  for (int i = tid; i < MBLK * 16; i += 256) {
    int r = i >> 4, k = 16 + (i & 15);
    hs[sw_idx(r, k)] = (_Float16)0.f;
  }
  stage4(wsh);         // prefetch layer-in kc0; drained by the barrier below
  __syncthreads();

  floatx4 acc[4][4];

  // R12 A-address strength reduction:
  //   byte(mt,kc) = (mt*16+col)*512 + qa*16 + ((kc^s2)<<6),
  //   s_a=(col^(col>>1))&7, s2=s_a>>2, qa=quad^(s_a&3); mt*8192 -> ds imm.
  const int s_a = (col ^ (col >> 1)) & 7;
  const int s2  = (s_a >> 2) & 1;
  const int abase = col * 512 + (quad ^ (s_a & 3)) * 16;
  const char* const hsb = (const char*)hs;
  // R17 b-read base: staged copy is verbatim, so b[nl] bytes are identical
  // to the old global loads. One 32-bit LDS address + nl*1KB immediates.
  const _Float16* const bsrc = &wstage[wave * 2048 + lane * 8];

  auto run_layer = [&](auto kc_const, const _Float16* __restrict__ wbase,
                       const float* __restrict__ bias_ptr,
                       const _Float16* __restrict__ next_wbase) {
    constexpr int KCOUNT = decltype(kc_const)::value;

    // R16 bias-in-acc-init: D layout col=lane&15 -> all 4 regs share n.
    {
      float bv[4];
      #pragma unroll
      for (int nl = 0; nl < 4; ++nl)
        bv[nl] = bias_ptr[wave * 64 + nl * 16 + col] * ALPHA;
      #pragma unroll
      for (int mt = 0; mt < 4; ++mt)
        #pragma unroll
        for (int nl = 0; nl < 4; ++nl)
          acc[mt][nl] = (floatx4){bv[nl], bv[nl], bv[nl], bv[nl]};
    }

    #pragma clang loop unroll(disable)               // keep VGPR pressure flat (<=128)
    for (int kc = 0; kc < KCOUNT; ++kc) {
      asm volatile("s_waitcnt vmcnt(0)" ::: "memory");   // staged kc arrived
      half8 b[4];
      #pragma unroll
      for (int nl = 0; nl < 4; ++nl)
        b[nl] = *(const half8*)(bsrc + nl * WNC_ELEMS);  // imm-offset ds_read_b128
      half8 a[4];
      const char* ap = hsb + abase + ((kc ^ s2) << 6);
      #pragma unroll
      for (int mt = 0; mt < 4; ++mt)
        a[mt] = *(const half8*)(ap + mt * 8192);         // imm-offset ds_read_b128
      asm volatile("s_waitcnt lgkmcnt(0)" ::: "memory"); // b,a in regs; buffer free
      if (kc + 1 < KCOUNT)
        stage4(wbase + (kc + 1) * WKC_ELEMS);            // DMA kc+1 under MFMA
      __builtin_amdgcn_s_setprio(1);
      #pragma unroll
      for (int nl = 0; nl < 4; ++nl)
        #pragma unroll
        for (int mt = 0; mt < 4; ++mt)
          acc[mt][nl] = __builtin_amdgcn_mfma_f32_16x16x32_f16(a[mt], b[nl], acc[mt][nl], 0, 0, 0);
      __builtin_amdgcn_s_setprio(0);
    }
    if (next_wbase) stage4(next_wbase);  // next layer kc0; drains at the barrier
    __syncthreads();   // all waves done reading hs before overwrite

    // R13 epilogue address strength reduction:
    //   byte = mt*8192 (ds imm) + (quad*4+r)*512 + wave*128 + ((v^s_r)<<4)
    //        + (col&7)*2,  v = nl*2|c3, s_r=(m0^(m0>>1))&7.
    {
      const int c3   = (col >> 3) & 1;
      const int ebase = wave * 128 + ((col & 7) << 1);
      #pragma unroll
      for (int nl = 0; nl < 4; ++nl) {
        #pragma unroll
        for (int r = 0; r < 4; ++r) {
          int m0  = quad * 4 + r;
          int s_r = (m0 ^ (m0 >> 1)) & 7;
          int va  = m0 * 512 + ebase + (((((nl << 1) | c3)) ^ s_r) << 4);
          char* wp = (char*)hs + va;
          #pragma unroll
          for (int mt = 0; mt < 4; ++mt) {
            float hv = fmaxf(acc[mt][nl][r], 0.f);           // ReLU pre-next-matmul
            *(_Float16*)(wp + mt * 8192) = (_Float16)hv;     // imm-offset ds_write_b16
          }
        }
      }
    }
    __syncthreads();
  };

  run_layer(std::integral_constant<int, 1>{}, wsh, b_in, wsh + WIN_ELEMS);
  #pragma clang loop unroll(disable)
  for (int L = 0; L < NMID; ++L)
    run_layer(std::integral_constant<int, 8>{}, wsh + WIN_ELEMS + L * WL_ELEMS,
              b_mid + L * DIM,
              (L < NMID - 1) ? (wsh + WIN_ELEMS + (L + 1) * WL_ELEMS) : nullptr);

  // ---------------- output layer: out = (alpha*relu h).W_out / alpha + b_out ----
  // R9 vectorized epilogue: 8x ds_read_b128 + 16x float4 W_out loads per thread.
  {
    int m = tid >> 2, seg = tid & 3;          // same-m threads adjacent -> shuffle reduce
    float sum = 0.f;
    #pragma unroll
    for (int i = 0; i < 8; ++i) {
      int k = (seg << 6) + (i << 3);          // 8-aligned group within this thread's 64-wide segment
      half8 hv = *(const half8*)&hs[sw_idx(m, k)];
      float4 w0 = *(const float4*)&W_out[k];
      float4 w1 = *(const float4*)&W_out[k + 4];
      sum += (float)hv[0] * w0.x + (float)hv[1] * w0.y
           + (float)hv[2] * w0.z + (float)hv[3] * w0.w
           + (float)hv[4] * w1.x + (float)hv[5] * w1.y
           + (float)hv[6] * w1.z + (float)hv[7] * w1.w;
    }
    sum += __shfl_xor(sum, 1);
    sum += __shfl_xor(sum, 2);
    if (seg == 0) out[rbase + m] = sum * INV_ALPHA + b_out[0];
  }
}

extern "C" void kernel_launch(void* const* d_in, const int* in_sizes, int n_in,
                              void* d_out, int out_size, void* d_ws, size_t ws_size,
                              hipStream_t stream)
{
  const float* x      = (const float*)d_in[0];
  const float* table1 = (const float*)d_in[1];
  const float* table2 = (const float*)d_in[2];
  const float* W_in   = (const float*)d_in[3];
  const float* b_in   = (const float*)d_in[4];
  const float* W_mid  = (const float*)d_in[5];
  const float* b_mid  = (const float*)d_in[6];
  const float* W_out  = (const float*)d_in[7];
  const float* b_out  = (const float*)d_in[8];
  float* out  = (float*)d_out;
  _Float16* wsh = (_Float16*)d_ws;

  // Resolutions: identical double-precision op sequence as the Python module (same libm).
  double b = exp((log(512.0) - log(16.0)) / 3.0);
  int res[4];
  for (int l = 0; l < 4; ++l) res[l] = (int)floor(16.0 * pow(b, (double)l));

  int prep_total = WIN_ELEMS + 6 * WL_ELEMS;   // 401408 = 1568 * 256
  prep_weights<<<prep_total / 256, 256, 0, stream>>>(W_in, W_mid, wsh);
  mlp_fused<<<NRAYS / MBLK, 256, 0, stream>>>(x, table1, table2, wsh, b_in, b_mid,
                                              W_out, b_out, out,
                                              res[0], res[1], res[2], res[3]);
}

// Round 10
// 283.829 us; speedup vs baseline: 1.2777x; 1.2777x over previous
//
#include <hip/hip_runtime.h>
#include <type_traits>
#include <cmath>
#include <cstdint>

#define NRAYS     262144
#define HASHMAP   524288
#define DIM       256
#define NMID      6
#define MBLK      64
#define ALPHA     512.0f          // power-of-2 activation scale: lifts h (~1e-4) out of
#define INV_ALPHA (1.0f / 512.0f) // fp16 subnormal range; exact, removed at output.

typedef _Float16 half8 __attribute__((ext_vector_type(8)));
typedef _Float16 half2 __attribute__((ext_vector_type(2)));
typedef float  floatx4 __attribute__((ext_vector_type(4)));

// ws layout (_Float16 elements) — fp16 weights, single product per MFMA:
//   [0, 8192):        W_in  fragments [nc:16][lane:64][j:8]  (K padded 16->32 with zeros)
//   [8192, 401408):   W_mid fragments [L:6][kc:8][nc:16][lane:64][j:8]
//
// SESSION INVARIANT (R10/R11/R14): the ~2-7e-6 few-elements-wrong miscompile
// class fires on ANY novel MFMA-loop register shape. The ONLY trusted
// micro-structure is R13's per-wave loop: b[4]+a[4] input regs, acc[4][4]
// floatx4, one setprio cluster, nl=4, unroll(disable) on kc. NEVER deviate.
//
// THEORY LEDGER (falsified hypotheses — do not revisit):
//   R15: weight L2 BANDWIDTH — halving traffic (MBLK=128) gave no gain.
//   R16: plain-VALU epilogue cost — VALUBusy==MfmaUtil => VALU ~= MFMA itself.
//   R17: global_load_lds staging — occupancy loss + hard vmcnt drains cost
//        more than the latency hidden (320us; VGPR 88, occupancy 22%).
//   R11/R14: register prefetch/deeper tiles — miscompile class.
// Remaining structure: each wave ~45% duty (310cyc MFMA vs ~380cyc exposed
// latency per kc); barriers convoy the rest. 222us is the R13-structure
// plateau; R18 trims only the non-layer phases.
//
// R12 (pass, 326us): strength-reduced A addressing + s_setprio.
// R13 (pass, 222us): strength-reduced epilogue addressing.  <- BASE
// R18: + W_out staged in LDS (output phase: 16 global float4/thread -> LDS
//      ds_read_b128; kills 268MB of L2 re-reads of the same 1KB) + float2
//      x-loads in encode. Zero register risk: both outside the frozen loop.
#define WIN_ELEMS   8192
#define WL_ELEMS    65536
#define WKC_ELEMS   8192
#define WNC_ELEMS   512

// Gray-coded XOR swizzle (R4, frozen — conflict counter insensitive to choice).
__device__ __forceinline__ int sw_idx(int r, int k) {
  int s = (r ^ (r >> 1)) & 7;
  return (r << 8) + ((((k >> 3) ^ s) << 3) | (k & 7));
}

__global__ __launch_bounds__(256) void prep_weights(
    const float* __restrict__ W_in, const float* __restrict__ W_mid,
    _Float16* __restrict__ wsh)
{
  int tid = blockIdx.x * 256 + threadIdx.x;
  int pos = tid & 511;             // lane*8 + j
  int lane = pos >> 3, j = pos & 7;
  int kk = ((lane >> 4) << 3) + j; // quad*8 + j, 0..31
  if (tid < WIN_ELEMS) {
    int nc = tid >> 9;
    int n = (nc << 4) + (lane & 15);
    float v = (kk < 16) ? W_in[kk * DIM + n] : 0.f;
    wsh[nc * WNC_ELEMS + pos] = (_Float16)v;
  } else if (tid < WIN_ELEMS + 6 * WL_ELEMS) {
    int u = tid - WIN_ELEMS;
    int fid = u >> 9;              // 0..767
    int L   = fid >> 7;
    int rem = fid & 127;
    int kc  = rem >> 4;
    int nc  = rem & 15;
    int k = (kc << 5) + kk;
    int n = (nc << 4) + (lane & 15);
    float v = W_mid[L * (DIM * DIM) + k * DIM + n];
    wsh[WIN_ELEMS + L * WL_ELEMS + kc * WKC_ELEMS + nc * WNC_ELEMS + pos] = (_Float16)v;
  }
}

// (256,4): VGPR cap 128 (the correctness invariant) AND 4 blocks/CU (33 KB LDS)
// for cross-block phase overlap. Latency hiding via TLP (16 waves/CU).
__global__ __launch_bounds__(256, 4) void mlp_fused(
    const float* __restrict__ x,
    const float* __restrict__ table1,
    const float* __restrict__ table2,
    const _Float16* __restrict__ wsh,
    const float* __restrict__ b_in,
    const float* __restrict__ b_mid,
    const float* __restrict__ W_out,
    const float* __restrict__ b_out,
    float* __restrict__ out,
    int res0, int res1, int res2, int res3)
{
  __shared__ __align__(16) _Float16 hs[MBLK * 256];  // 32KB: alpha*relu(h) fp16, swizzled [ray][k]
  __shared__ __align__(16) float wout_s[DIM];        // 1KB: staged W_out (R18)

  const int tid  = threadIdx.x;
  const int lane = tid & 63;
  const int wave = tid >> 6;
  const int col  = lane & 15;
  const int quad = lane >> 4;
  const int rbase = blockIdx.x * MBLK;

  wout_s[tid] = W_out[tid];        // R18: one coalesced load; used after last barrier

  // ---------------- hash-grid encode: 512 (ray,enc,level) tasks, 2 per thread ----------------
  #pragma unroll
  for (int i = 0; i < 2; ++i) {
    int task = tid + (i << 8);
    int r   = task & 63;
    int el  = task >> 6;           // 0..7
    int enc = el >> 2, lev = el & 3;
    const float2 p2 = *(const float2*)(x + (size_t)(rbase + r) * 4 + enc * 2);  // R18: dwordx2
    float px = p2.x, py = p2.y;
    int res = (lev == 0) ? res0 : (lev == 1) ? res1 : (lev == 2) ? res2 : res3;
    float fres = (float)res;
    float xf = px * fres, yf = py * fres;
    float xi = floorf(xf), yi = floorf(yf);
    float fx = xf - xi,  fy = yf - yi;
    uint32_t ix = (uint32_t)xi, iy = (uint32_t)yi;
    const float2* tab = (const float2*)(enc ? table2 : table1) + (size_t)lev * HASHMAP;
    float f0 = 0.f, f1 = 0.f;
    #pragma unroll
    for (int c = 0; c < 4; ++c) {                    // corners (0,0),(0,1),(1,0),(1,1)
      uint32_t c0 = (uint32_t)(c >> 1), c1 = (uint32_t)(c & 1);
      uint32_t h = ((ix + c0) ^ ((iy + c1) * 2654435761u)) & (uint32_t)(HASHMAP - 1);
      float2 v = tab[h];
      float w = (c0 ? fx : 1.f - fx) * (c1 ? fy : 1.f - fy);
      f0 += w * v.x;
      f1 += w * v.y;
    }
    int cb = enc * 8 + lev * 2;                      // emb column (concat: enc-major, level, feat)
    half2 hp = {(_Float16)(f0 * ALPHA), (_Float16)(f1 * ALPHA)};
    *(half2*)&hs[sw_idx(r, cb)] = hp;
  }
  // zero K-pad columns 16..31 for the first (K=32) MFMA
  for (int i = tid; i < MBLK * 16; i += 256) {
    int r = i >> 4, k = 16 + (i & 15);
    hs[sw_idx(r, k)] = (_Float16)0.f;
  }
  __syncthreads();

  floatx4 acc[4][4];

  // R12 A-address strength reduction. For A-reads, row = mt*16+col so row&7 =
  // col&7 and sw_idx's s is mt-independent:
  //   byte(mt,kc) = (mt*16+col)*512 + qa*16 + ((kc^s2)<<6)
  //   s_a=(col^(col>>1))&7, s2=s_a>>2, qa=quad^(s_a&3).
  // mt term (mt*8192) folds into the ds_read immediate offset.
  const int s_a = (col ^ (col >> 1)) & 7;
  const int s2  = (s_a >> 2) & 1;
  const int abase = col * 512 + (quad ^ (s_a & 3)) * 16;
  const char* const hsb = (const char*)hs;

  // One dense layer: D(64x256) = A(64xK) * B(Kx256); A = alpha*h (fp16, LDS),
  // B = fp16 weights (pre-permuted fragments, L2-resident).
  auto run_layer = [&](auto kc_const, const _Float16* __restrict__ wbase,
                       const float* __restrict__ bias_ptr) {
    constexpr int KCOUNT = decltype(kc_const)::value;
    const floatx4 zv = {0.f, 0.f, 0.f, 0.f};
    #pragma unroll
    for (int mt = 0; mt < 4; ++mt)
      #pragma unroll
      for (int nl = 0; nl < 4; ++nl)
        acc[mt][nl] = zv;

    const _Float16* wlane = wbase + wave * 4 * WNC_ELEMS + lane * 8;

    #pragma clang loop unroll(disable)               // keep VGPR pressure flat (<=128)
    for (int kc = 0; kc < KCOUNT; ++kc) {
      half8 b[4];
      const _Float16* wk = wlane + kc * WKC_ELEMS;
      #pragma unroll
      for (int nl = 0; nl < 4; ++nl)
        b[nl] = *(const half8*)(wk + nl * WNC_ELEMS);
      half8 a[4];
      const char* ap = hsb + abase + ((kc ^ s2) << 6);
      #pragma unroll
      for (int mt = 0; mt < 4; ++mt)
        a[mt] = *(const half8*)(ap + mt * 8192);     // imm-offset ds_read_b128
      __builtin_amdgcn_s_setprio(1);
      #pragma unroll
      for (int nl = 0; nl < 4; ++nl)
        #pragma unroll
        for (int mt = 0; mt < 4; ++mt)
          acc[mt][nl] = __builtin_amdgcn_mfma_f32_16x16x32_f16(a[mt], b[nl], acc[mt][nl], 0, 0, 0);
      __builtin_amdgcn_s_setprio(0);
    }
    __syncthreads();   // all waves done reading hs before overwrite

    // R13 epilogue address strength reduction. Write target (m,n):
    //   m = mt*16 + quad*4 + r, n = wave*64 + nl*16 + col.
    //   byte = mt*8192 (ds imm) + (quad*4+r)*512 + wave*128
    //        + ((v^s_r)<<4) + (col&7)*2,  v = nl*2|c3, s_r=(m0^(m0>>1))&7.
    {
      const int c3   = (col >> 3) & 1;
      const int ebase = wave * 128 + ((col & 7) << 1);
      #pragma unroll
      for (int nl = 0; nl < 4; ++nl) {
        int n = wave * 64 + nl * 16 + col;
        float biasA = bias_ptr[n] * ALPHA;           // bias scaled by alpha
        #pragma unroll
        for (int r = 0; r < 4; ++r) {
          int m0  = quad * 4 + r;
          int s_r = (m0 ^ (m0 >> 1)) & 7;
          int va  = m0 * 512 + ebase + (((((nl << 1) | c3)) ^ s_r) << 4);
          char* wp = (char*)hs + va;
          #pragma unroll
          for (int mt = 0; mt < 4; ++mt) {
            float hv = fmaxf(acc[mt][nl][r] + biasA, 0.f);   // ReLU pre-next-matmul
            *(_Float16*)(wp + mt * 8192) = (_Float16)hv;     // imm-offset ds_write_b16
          }
        }
      }
    }
    __syncthreads();
  };

  run_layer(std::integral_constant<int, 1>{}, wsh, b_in);
  #pragma clang loop unroll(disable)
  for (int L = 0; L < NMID; ++L)
    run_layer(std::integral_constant<int, 8>{}, wsh + WIN_ELEMS + L * WL_ELEMS, b_mid + L * DIM);

  // ---------------- output layer: out = (alpha*relu h).W_out / alpha + b_out ----
  // R9 vectorized epilogue; R18: W_out from LDS stage (imm-offset ds_read_b128).
  {
    int m = tid >> 2, seg = tid & 3;          // same-m threads adjacent -> shuffle reduce
    float sum = 0.f;
    #pragma unroll
    for (int i = 0; i < 8; ++i) {
      int k = (seg << 6) + (i << 3);          // 8-aligned group within this thread's 64-wide segment
      half8 hv = *(const half8*)&hs[sw_idx(m, k)];
      float4 w0 = *(const float4*)&wout_s[k];
      float4 w1 = *(const float4*)&wout_s[k + 4];
      sum += (float)hv[0] * w0.x + (float)hv[1] * w0.y
           + (float)hv[2] * w0.z + (float)hv[3] * w0.w
           + (float)hv[4] * w1.x + (float)hv[5] * w1.y
           + (float)hv[6] * w1.z + (float)hv[7] * w1.w;
    }
    sum += __shfl_xor(sum, 1);
    sum += __shfl_xor(sum, 2);
    if (seg == 0) out[rbase + m] = sum * INV_ALPHA + b_out[0];
  }
}

extern "C" void kernel_launch(void* const* d_in, const int* in_sizes, int n_in,
                              void* d_out, int out_size, void* d_ws, size_t ws_size,
                              hipStream_t stream)
{
  const float* x      = (const float*)d_in[0];
  const float* table1 = (const float*)d_in[1];
  const float* table2 = (const float*)d_in[2];
  const float* W_in   = (const float*)d_in[3];
  const float* b_in   = (const float*)d_in[4];
  const float* W_mid  = (const float*)d_in[5];
  const float* b_mid  = (const float*)d_in[6];
  const float* W_out  = (const float*)d_in[7];
  const float* b_out  = (const float*)d_in[8];
  float* out  = (float*)d_out;
  _Float16* wsh = (_Float16*)d_ws;

  // Resolutions: identical double-precision op sequence as the Python module (same libm).
  double b = exp((log(512.0) - log(16.0)) / 3.0);
  int res[4];
  for (int l = 0; l < 4; ++l) res[l] = (int)floor(16.0 * pow(b, (double)l));

  int prep_total = WIN_ELEMS + 6 * WL_ELEMS;   // 401408 = 1568 * 256
  prep_weights<<<prep_total / 256, 256, 0, stream>>>(W_in, W_mid, wsh);
  mlp_fused<<<NRAYS / MBLK, 256, 0, stream>>>(x, table1, table2, wsh, b_in, b_mid,
                                              W_out, b_out, out,
                                              res[0], res[1], res[2], res[3]);
}

// Round 11
// 282.313 us; speedup vs baseline: 1.2845x; 1.0054x over previous
//
#include <hip/hip_runtime.h>
#include <type_traits>
#include <cmath>
#include <cstdint>

#define NRAYS     262144
#define HASHMAP   524288
#define DIM       256
#define NMID      6
#define MBLK      64
#define ALPHA     512.0f          // power-of-2 activation scale: lifts h (~1e-4) out of
#define INV_ALPHA (1.0f / 512.0f) // fp16 subnormal range; exact, removed at output.

typedef _Float16 half8 __attribute__((ext_vector_type(8)));
typedef _Float16 half2 __attribute__((ext_vector_type(2)));
typedef float  floatx4 __attribute__((ext_vector_type(4)));

// ws layout (_Float16 elements) — fp16 weights, single product per MFMA:
//   [0, 8192):        W_in  fragments [nc:16][lane:64][j:8]  (K padded 16->32 with zeros)
//   [8192, 401408):   W_mid fragments [L:6][kc:8][nc:16][lane:64][j:8]
//
// SESSION INVARIANT (R10/R11/R14): the ~2-7e-6 few-elements-wrong miscompile
// class fires when the MFMA loop's live register set grows beyond b[4]+a[4]
// (+acc[4][4] floatx4). Trusted structure: those exact variables, nl=4, one
// setprio region, unroll(disable) on kc.
//
// THEORY LEDGER (falsified — do not revisit):
//   R15: weight L2 BANDWIDTH (MBLK=128, halved traffic, no gain)
//   R16: plain-VALU epilogue cost (VALUBusy==MfmaUtil => VALU ~= MFMA)
//   R17: global_load_lds staging (occupancy + hard-drain cost > latency saved)
//   R11/R14: register double-buffers / reshaped tiles (miscompile class)
//
// R12 (pass, 326us): strength-reduced A addressing + s_setprio.
// R13 (pass, 222us): strength-reduced epilogue addressing.
// R18 (pass, 205us): W_out staged in LDS + float2 x-loads.  <- BASE
// R19: zero-register modulo schedule of the b-loads. Cluster nl is the LAST
//   reader of b[nl], so b[nl] is dead right after its 4 MFMAs: load kc+1's
//   fragment into the same variable there. Live set stays exactly b[4]+a[4]
//   (32 regs) at every point — nothing added, loads only MOVED to where their
//   destination dies. Removes the per-kc WAR stall (the remaining 2x vs the
//   ~100us MFMA floor). Arithmetic order unchanged -> absmax must be exactly
//   1.192093e-07 (miscompile tripwire; any deviation => revert to R18).
#define WIN_ELEMS   8192
#define WL_ELEMS    65536
#define WKC_ELEMS   8192
#define WNC_ELEMS   512

// Gray-coded XOR swizzle (R4, frozen — conflict counter insensitive to choice).
__device__ __forceinline__ int sw_idx(int r, int k) {
  int s = (r ^ (r >> 1)) & 7;
  return (r << 8) + ((((k >> 3) ^ s) << 3) | (k & 7));
}

__global__ __launch_bounds__(256) void prep_weights(
    const float* __restrict__ W_in, const float* __restrict__ W_mid,
    _Float16* __restrict__ wsh)
{
  int tid = blockIdx.x * 256 + threadIdx.x;
  int pos = tid & 511;             // lane*8 + j
  int lane = pos >> 3, j = pos & 7;
  int kk = ((lane >> 4) << 3) + j; // quad*8 + j, 0..31
  if (tid < WIN_ELEMS) {
    int nc = tid >> 9;
    int n = (nc << 4) + (lane & 15);
    float v = (kk < 16) ? W_in[kk * DIM + n] : 0.f;
    wsh[nc * WNC_ELEMS + pos] = (_Float16)v;
  } else if (tid < WIN_ELEMS + 6 * WL_ELEMS) {
    int u = tid - WIN_ELEMS;
    int fid = u >> 9;              // 0..767
    int L   = fid >> 7;
    int rem = fid & 127;
    int kc  = rem >> 4;
    int nc  = rem & 15;
    int k = (kc << 5) + kk;
    int n = (nc << 4) + (lane & 15);
    float v = W_mid[L * (DIM * DIM) + k * DIM + n];
    wsh[WIN_ELEMS + L * WL_ELEMS + kc * WKC_ELEMS + nc * WNC_ELEMS + pos] = (_Float16)v;
  }
}

// (256,4): VGPR cap 128 (the correctness invariant) AND 4 blocks/CU (33 KB LDS)
// for cross-block phase overlap. Latency hiding via TLP (16 waves/CU) + R19's
// distance-1 b rotation.
__global__ __launch_bounds__(256, 4) void mlp_fused(
    const float* __restrict__ x,
    const float* __restrict__ table1,
    const float* __restrict__ table2,
    const _Float16* __restrict__ wsh,
    const float* __restrict__ b_in,
    const float* __restrict__ b_mid,
    const float* __restrict__ W_out,
    const float* __restrict__ b_out,
    float* __restrict__ out,
    int res0, int res1, int res2, int res3)
{
  __shared__ __align__(16) _Float16 hs[MBLK * 256];  // 32KB: alpha*relu(h) fp16, swizzled [ray][k]
  __shared__ __align__(16) float wout_s[DIM];        // 1KB: staged W_out (R18)

  const int tid  = threadIdx.x;
  const int lane = tid & 63;
  const int wave = tid >> 6;
  const int col  = lane & 15;
  const int quad = lane >> 4;
  const int rbase = blockIdx.x * MBLK;

  wout_s[tid] = W_out[tid];        // R18: one coalesced load; used after last barrier

  // ---------------- hash-grid encode: 512 (ray,enc,level) tasks, 2 per thread ----------------
  #pragma unroll
  for (int i = 0; i < 2; ++i) {
    int task = tid + (i << 8);
    int r   = task & 63;
    int el  = task >> 6;           // 0..7
    int enc = el >> 2, lev = el & 3;
    const float2 p2 = *(const float2*)(x + (size_t)(rbase + r) * 4 + enc * 2);  // R18: dwordx2
    float px = p2.x, py = p2.y;
    int res = (lev == 0) ? res0 : (lev == 1) ? res1 : (lev == 2) ? res2 : res3;
    float fres = (float)res;
    float xf = px * fres, yf = py * fres;
    float xi = floorf(xf), yi = floorf(yf);
    float fx = xf - xi,  fy = yf - yi;
    uint32_t ix = (uint32_t)xi, iy = (uint32_t)yi;
    const float2* tab = (const float2*)(enc ? table2 : table1) + (size_t)lev * HASHMAP;
    float f0 = 0.f, f1 = 0.f;
    #pragma unroll
    for (int c = 0; c < 4; ++c) {                    // corners (0,0),(0,1),(1,0),(1,1)
      uint32_t c0 = (uint32_t)(c >> 1), c1 = (uint32_t)(c & 1);
      uint32_t h = ((ix + c0) ^ ((iy + c1) * 2654435761u)) & (uint32_t)(HASHMAP - 1);
      float2 v = tab[h];
      float w = (c0 ? fx : 1.f - fx) * (c1 ? fy : 1.f - fy);
      f0 += w * v.x;
      f1 += w * v.y;
    }
    int cb = enc * 8 + lev * 2;                      // emb column (concat: enc-major, level, feat)
    half2 hp = {(_Float16)(f0 * ALPHA), (_Float16)(f1 * ALPHA)};
    *(half2*)&hs[sw_idx(r, cb)] = hp;
  }
  // zero K-pad columns 16..31 for the first (K=32) MFMA
  for (int i = tid; i < MBLK * 16; i += 256) {
    int r = i >> 4, k = 16 + (i & 15);
    hs[sw_idx(r, k)] = (_Float16)0.f;
  }
  __syncthreads();

  floatx4 acc[4][4];

  // R12 A-address strength reduction. For A-reads, row = mt*16+col so row&7 =
  // col&7 and sw_idx's s is mt-independent:
  //   byte(mt,kc) = (mt*16+col)*512 + qa*16 + ((kc^s2)<<6)
  //   s_a=(col^(col>>1))&7, s2=s_a>>2, qa=quad^(s_a&3).
  // mt term (mt*8192) folds into the ds_read immediate offset.
  const int s_a = (col ^ (col >> 1)) & 7;
  const int s2  = (s_a >> 2) & 1;
  const int abase = col * 512 + (quad ^ (s_a & 3)) * 16;
  const char* const hsb = (const char*)hs;

  // One dense layer: D(64x256) = A(64xK) * B(Kx256); A = alpha*h (fp16, LDS),
  // B = fp16 weights (pre-permuted fragments, L2/L1-resident).
  auto run_layer = [&](auto kc_const, const _Float16* __restrict__ wbase,
                       const float* __restrict__ bias_ptr) {
    constexpr int KCOUNT = decltype(kc_const)::value;
    const floatx4 zv = {0.f, 0.f, 0.f, 0.f};
    #pragma unroll
    for (int mt = 0; mt < 4; ++mt)
      #pragma unroll
      for (int nl = 0; nl < 4; ++nl)
        acc[mt][nl] = zv;

    const _Float16* wlane = wbase + wave * 4 * WNC_ELEMS + lane * 8;

    if constexpr (KCOUNT == 1) {
      // R13 body verbatim (single kc, no rotation).
      half8 b[4];
      #pragma unroll
      for (int nl = 0; nl < 4; ++nl)
        b[nl] = *(const half8*)(wlane + nl * WNC_ELEMS);
      half8 a[4];
      const char* ap = hsb + abase;                  // kc=0: (0^s2)<<6 folds into s2 term
      #pragma unroll
      for (int mt = 0; mt < 4; ++mt)
        a[mt] = *(const half8*)(ap + (s2 << 6) + mt * 8192);
      __builtin_amdgcn_s_setprio(1);
      #pragma unroll
      for (int nl = 0; nl < 4; ++nl)
        #pragma unroll
        for (int mt = 0; mt < 4; ++mt)
          acc[mt][nl] = __builtin_amdgcn_mfma_f32_16x16x32_f16(a[mt], b[nl], acc[mt][nl], 0, 0, 0);
      __builtin_amdgcn_s_setprio(0);
    } else {
      // R19 rotation: b[nl] reloaded for kc+1 immediately after its last use.
      // Live set identical to R13: 4 b + 4 a at every point. Same MFMA order.
      half8 b0 = *(const half8*)(wlane + 0 * WNC_ELEMS);
      half8 b1 = *(const half8*)(wlane + 1 * WNC_ELEMS);
      half8 b2 = *(const half8*)(wlane + 2 * WNC_ELEMS);
      half8 b3 = *(const half8*)(wlane + 3 * WNC_ELEMS);
      #pragma clang loop unroll(disable)             // keep VGPR pressure flat (<=128)
      for (int kc = 0; kc < KCOUNT; ++kc) {
        half8 a[4];
        const char* ap = hsb + abase + ((kc ^ s2) << 6);
        #pragma unroll
        for (int mt = 0; mt < 4; ++mt)
          a[mt] = *(const half8*)(ap + mt * 8192);   // imm-offset ds_read_b128
        // branchless next-kc pointer: last iteration harmlessly re-reads kc0
        // (values dead at loop exit; L1-hot; no OOB).
        const _Float16* wn = wlane + ((kc + 1 < KCOUNT) ? (kc + 1) * WKC_ELEMS : 0);
        __builtin_amdgcn_s_setprio(1);
        acc[0][0] = __builtin_amdgcn_mfma_f32_16x16x32_f16(a[0], b0, acc[0][0], 0, 0, 0);
        acc[1][0] = __builtin_amdgcn_mfma_f32_16x16x32_f16(a[1], b0, acc[1][0], 0, 0, 0);
        acc[2][0] = __builtin_amdgcn_mfma_f32_16x16x32_f16(a[2], b0, acc[2][0], 0, 0, 0);
        acc[3][0] = __builtin_amdgcn_mfma_f32_16x16x32_f16(a[3], b0, acc[3][0], 0, 0, 0);
        b0 = *(const half8*)(wn + 0 * WNC_ELEMS);    // b0 dead -> prefetch kc+1
        acc[0][1] = __builtin_amdgcn_mfma_f32_16x16x32_f16(a[0], b1, acc[0][1], 0, 0, 0);
        acc[1][1] = __builtin_amdgcn_mfma_f32_16x16x32_f16(a[1], b1, acc[1][1], 0, 0, 0);
        acc[2][1] = __builtin_amdgcn_mfma_f32_16x16x32_f16(a[2], b1, acc[2][1], 0, 0, 0);
        acc[3][1] = __builtin_amdgcn_mfma_f32_16x16x32_f16(a[3], b1, acc[3][1], 0, 0, 0);
        b1 = *(const half8*)(wn + 1 * WNC_ELEMS);
        acc[0][2] = __builtin_amdgcn_mfma_f32_16x16x32_f16(a[0], b2, acc[0][2], 0, 0, 0);
        acc[1][2] = __builtin_amdgcn_mfma_f32_16x16x32_f16(a[1], b2, acc[1][2], 0, 0, 0);
        acc[2][2] = __builtin_amdgcn_mfma_f32_16x16x32_f16(a[2], b2, acc[2][2], 0, 0, 0);
        acc[3][2] = __builtin_amdgcn_mfma_f32_16x16x32_f16(a[3], b2, acc[3][2], 0, 0, 0);
        b2 = *(const half8*)(wn + 2 * WNC_ELEMS);
        acc[0][3] = __builtin_amdgcn_mfma_f32_16x16x32_f16(a[0], b3, acc[0][3], 0, 0, 0);
        acc[1][3] = __builtin_amdgcn_mfma_f32_16x16x32_f16(a[1], b3, acc[1][3], 0, 0, 0);
        acc[2][3] = __builtin_amdgcn_mfma_f32_16x16x32_f16(a[2], b3, acc[2][3], 0, 0, 0);
        acc[3][3] = __builtin_amdgcn_mfma_f32_16x16x32_f16(a[3], b3, acc[3][3], 0, 0, 0);
        b3 = *(const half8*)(wn + 3 * WNC_ELEMS);
        __builtin_amdgcn_s_setprio(0);
      }
    }
    __syncthreads();   // all waves done reading hs before overwrite

    // R13 epilogue address strength reduction. Write target (m,n):
    //   m = mt*16 + quad*4 + r, n = wave*64 + nl*16 + col.
    //   byte = mt*8192 (ds imm) + (quad*4+r)*512 + wave*128
    //        + ((v^s_r)<<4) + (col&7)*2,  v = nl*2|c3, s_r=(m0^(m0>>1))&7.
    {
      const int c3   = (col >> 3) & 1;
      const int ebase = wave * 128 + ((col & 7) << 1);
      #pragma unroll
      for (int nl = 0; nl < 4; ++nl) {
        int n = wave * 64 + nl * 16 + col;
        float biasA = bias_ptr[n] * ALPHA;           // bias scaled by alpha
        #pragma unroll
        for (int r = 0; r < 4; ++r) {
          int m0  = quad * 4 + r;
          int s_r = (m0 ^ (m0 >> 1)) & 7;
          int va  = m0 * 512 + ebase + (((((nl << 1) | c3)) ^ s_r) << 4);
          char* wp = (char*)hs + va;
          #pragma unroll
          for (int mt = 0; mt < 4; ++mt) {
            float hv = fmaxf(acc[mt][nl][r] + biasA, 0.f);   // ReLU pre-next-matmul
            *(_Float16*)(wp + mt * 8192) = (_Float16)hv;     // imm-offset ds_write_b16
          }
        }
      }
    }
    __syncthreads();
  };

  run_layer(std::integral_constant<int, 1>{}, wsh, b_in);
  #pragma clang loop unroll(disable)
  for (int L = 0; L < NMID; ++L)
    run_layer(std::integral_constant<int, 8>{}, wsh + WIN_ELEMS + L * WL_ELEMS, b_mid + L * DIM);

  // ---------------- output layer: out = (alpha*relu h).W_out / alpha + b_out ----
  // R9 vectorized epilogue; R18: W_out from LDS stage (imm-offset ds_read_b128).
  {
    int m = tid >> 2, seg = tid & 3;          // same-m threads adjacent -> shuffle reduce
    float sum = 0.f;
    #pragma unroll
    for (int i = 0; i < 8; ++i) {
      int k = (seg << 6) + (i << 3);          // 8-aligned group within this thread's 64-wide segment
      half8 hv = *(const half8*)&hs[sw_idx(m, k)];
      float4 w0 = *(const float4*)&wout_s[k];
      float4 w1 = *(const float4*)&wout_s[k + 4];
      sum += (float)hv[0] * w0.x + (float)hv[1] * w0.y
           + (float)hv[2] * w0.z + (float)hv[3] * w0.w
           + (float)hv[4] * w1.x + (float)hv[5] * w1.y
           + (float)hv[6] * w1.z + (float)hv[7] * w1.w;
    }
    sum += __shfl_xor(sum, 1);
    sum += __shfl_xor(sum, 2);
    if (seg == 0) out[rbase + m] = sum * INV_ALPHA + b_out[0];
  }
}

extern "C" void kernel_launch(void* const* d_in, const int* in_sizes, int n_in,
                              void* d_out, int out_size, void* d_ws, size_t ws_size,
                              hipStream_t stream)
{
  const float* x      = (const float*)d_in[0];
  const float* table1 = (const float*)d_in[1];
  const float* table2 = (const float*)d_in[2];
  const float* W_in   = (const float*)d_in[3];
  const float* b_in   = (const float*)d_in[4];
  const float* W_mid  = (const float*)d_in[5];
  const float* b_mid  = (const float*)d_in[6];
  const float* W_out  = (const float*)d_in[7];
  const float* b_out  = (const float*)d_in[8];
  float* out  = (float*)d_out;
  _Float16* wsh = (_Float16*)d_ws;

  // Resolutions: identical double-precision op sequence as the Python module (same libm).
  double b = exp((log(512.0) - log(16.0)) / 3.0);
  int res[4];
  for (int l = 0; l < 4; ++l) res[l] = (int)floor(16.0 * pow(b, (double)l));

  int prep_total = WIN_ELEMS + 6 * WL_ELEMS;   // 401408 = 1568 * 256
  prep_weights<<<prep_total / 256, 256, 0, stream>>>(W_in, W_mid, wsh);
  mlp_fused<<<NRAYS / MBLK, 256, 0, stream>>>(x, table1, table2, wsh, b_in, b_mid,
                                              W_out, b_out, out,
                                              res[0], res[1], res[2], res[3]);
}

// Round 12
// 281.036 us; speedup vs baseline: 1.2904x; 1.0045x over previous
//
#include <hip/hip_runtime.h>
#include <type_traits>
#include <cmath>
#include <cstdint>

#define NRAYS     262144
#define HASHMAP   524288
#define DIM       256
#define NMID      6
#define MBLK      64
#define ALPHA     512.0f          // power-of-2 activation scale: lifts h (~1e-4) out of
#define INV_ALPHA (1.0f / 512.0f) // fp16 subnormal range; exact, removed at output.

typedef _Float16 half8 __attribute__((ext_vector_type(8)));
typedef _Float16 half2 __attribute__((ext_vector_type(2)));
typedef float  floatx4 __attribute__((ext_vector_type(4)));

// ws layout (_Float16 elements) — fp16 weights, single product per MFMA:
//   [0, 8192):        W_in  fragments [nc:16][lane:64][j:8]  (K padded 16->32 with zeros)
//   [8192, 401408):   W_mid fragments [L:6][kc:8][nc:16][lane:64][j:8]
//
// SESSION INVARIANT (R10/R11/R14): the ~2-7e-6 few-elements-wrong miscompile
// class fires when the MFMA loop's live register set grows beyond b[4]+a[4]
// (+acc[4][4] floatx4). Trusted structure: those exact variables, nl=4, one
// setprio region, unroll(disable) on kc. NEVER deviate.
//
// THEORY LEDGER (falsified — do not revisit):
//   R15: weight L2 BANDWIDTH (MBLK=128, halved traffic, no gain)
//   R16: plain-VALU epilogue cost (VALUBusy==MfmaUtil => VALU ~= MFMA)
//   R17: global_load_lds staging (occupancy + hard-drain cost > latency saved)
//   R19: per-kc b-load latency (distance-1 rotation: absmax exact, -5% perf
//        => loads were already hidden; don't break the MFMA issue burst)
//   R11/R14: register double-buffers / reshaped tiles (miscompile class)
// Cycle audit @205us (492k cyc/CU): MFMA pipe 49%, LDS pipe ~52%, VALU ~2%.
// Two half-busy pipes serialized within-wave; breaking it needs register
// shapes the miscompile class forbids. mlp is at its structural plateau.
//
// R12 (pass, 326us): strength-reduced A addressing + s_setprio.
// R13 (pass, 222us): strength-reduced epilogue addressing.
// R18 (pass, 205us): W_out staged in LDS + float2 x-loads.  <- mlp FINAL
// R20: mlp = R18 verbatim. prep_weights rewritten source-coalesced (thread =
//   source element, destination computed by the inverse fragment mapping):
//   the old kernel strided 1KB between consecutive threads on W_mid reads.
//   Bijection verified algebraically (incl. W_in zero-pad region).
#define WIN_ELEMS   8192
#define WL_ELEMS    65536
#define WKC_ELEMS   8192
#define WNC_ELEMS   512

// Gray-coded XOR swizzle (R4, frozen — conflict counter insensitive to choice).
__device__ __forceinline__ int sw_idx(int r, int k) {
  int s = (r ^ (r >> 1)) & 7;
  return (r << 8) + ((((k >> 3) ^ s) << 3) | (k & 7));
}

// R20: coalesced prep. u enumerates: [0,4096) W_in elements, [4096,8192)
// W_in K-pad zeros (kk 16..31), [8192,401408) W_mid elements (u-8192 linear
// over [L][k][n] -> coalesced reads). dst = identical fragment mapping as the
// old forward kernel: quad=kk>>3, j=kk&7, nc=n>>4, lane=(quad<<4)|(n&15),
// dst = region + nc*WNC + lane*8 + j.
__global__ __launch_bounds__(256) void prep_weights(
    const float* __restrict__ W_in, const float* __restrict__ W_mid,
    _Float16* __restrict__ wsh)
{
  int u = blockIdx.x * 256 + threadIdx.x;
  if (u < 4096) {                      // W_in: k = u>>8 (0..15), n = u&255
    int k = u >> 8, n = u & 255;
    float v = W_in[u];                 // coalesced (n fastest)
    int quad = k >> 3, j = k & 7;
    int nc = n >> 4, lane = (quad << 4) | (n & 15);
    wsh[nc * WNC_ELEMS + lane * 8 + j] = (_Float16)v;
  } else if (u < 8192) {               // K-pad zeros: kk = 16 + (u-4096)>>8
    int r2 = u - 4096;
    int kk = 16 + (r2 >> 8), n = r2 & 255;
    int quad = kk >> 3, j = kk & 7;
    int nc = n >> 4, lane = (quad << 4) | (n & 15);
    wsh[nc * WNC_ELEMS + lane * 8 + j] = (_Float16)0.f;
  } else {                             // W_mid: um linear over [L][k][n]
    int um = u - 8192;
    int L = um >> 16;
    int rem = um & 65535;
    int k = rem >> 8, n = rem & 255;
    float v = W_mid[um];               // coalesced (n fastest)
    int kc = k >> 5, kk = k & 31;
    int quad = kk >> 3, j = kk & 7;
    int nc = n >> 4, lane = (quad << 4) | (n & 15);
    wsh[WIN_ELEMS + L * WL_ELEMS + kc * WKC_ELEMS + nc * WNC_ELEMS + lane * 8 + j]
        = (_Float16)v;
  }
}

// (256,4): VGPR cap 128 (the correctness invariant) AND 4 blocks/CU (33 KB LDS)
// for cross-block phase overlap. Latency hiding via TLP (16 waves/CU).
__global__ __launch_bounds__(256, 4) void mlp_fused(
    const float* __restrict__ x,
    const float* __restrict__ table1,
    const float* __restrict__ table2,
    const _Float16* __restrict__ wsh,
    const float* __restrict__ b_in,
    const float* __restrict__ b_mid,
    const float* __restrict__ W_out,
    const float* __restrict__ b_out,
    float* __restrict__ out,
    int res0, int res1, int res2, int res3)
{
  __shared__ __align__(16) _Float16 hs[MBLK * 256];  // 32KB: alpha*relu(h) fp16, swizzled [ray][k]
  __shared__ __align__(16) float wout_s[DIM];        // 1KB: staged W_out (R18)

  const int tid  = threadIdx.x;
  const int lane = tid & 63;
  const int wave = tid >> 6;
  const int col  = lane & 15;
  const int quad = lane >> 4;
  const int rbase = blockIdx.x * MBLK;

  wout_s[tid] = W_out[tid];        // R18: one coalesced load; used after last barrier

  // ---------------- hash-grid encode: 512 (ray,enc,level) tasks, 2 per thread ----------------
  #pragma unroll
  for (int i = 0; i < 2; ++i) {
    int task = tid + (i << 8);
    int r   = task & 63;
    int el  = task >> 6;           // 0..7
    int enc = el >> 2, lev = el & 3;
    const float2 p2 = *(const float2*)(x + (size_t)(rbase + r) * 4 + enc * 2);  // R18: dwordx2
    float px = p2.x, py = p2.y;
    int res = (lev == 0) ? res0 : (lev == 1) ? res1 : (lev == 2) ? res2 : res3;
    float fres = (float)res;
    float xf = px * fres, yf = py * fres;
    float xi = floorf(xf), yi = floorf(yf);
    float fx = xf - xi,  fy = yf - yi;
    uint32_t ix = (uint32_t)xi, iy = (uint32_t)yi;
    const float2* tab = (const float2*)(enc ? table2 : table1) + (size_t)lev * HASHMAP;
    float f0 = 0.f, f1 = 0.f;
    #pragma unroll
    for (int c = 0; c < 4; ++c) {                    // corners (0,0),(0,1),(1,0),(1,1)
      uint32_t c0 = (uint32_t)(c >> 1), c1 = (uint32_t)(c & 1);
      uint32_t h = ((ix + c0) ^ ((iy + c1) * 2654435761u)) & (uint32_t)(HASHMAP - 1);
      float2 v = tab[h];
      float w = (c0 ? fx : 1.f - fx) * (c1 ? fy : 1.f - fy);
      f0 += w * v.x;
      f1 += w * v.y;
    }
    int cb = enc * 8 + lev * 2;                      // emb column (concat: enc-major, level, feat)
    half2 hp = {(_Float16)(f0 * ALPHA), (_Float16)(f1 * ALPHA)};
    *(half2*)&hs[sw_idx(r, cb)] = hp;
  }
  // zero K-pad columns 16..31 for the first (K=32) MFMA
  for (int i = tid; i < MBLK * 16; i += 256) {
    int r = i >> 4, k = 16 + (i & 15);
    hs[sw_idx(r, k)] = (_Float16)0.f;
  }
  __syncthreads();

  floatx4 acc[4][4];

  // R12 A-address strength reduction. For A-reads, row = mt*16+col so row&7 =
  // col&7 and sw_idx's s is mt-independent:
  //   byte(mt,kc) = (mt*16+col)*512 + qa*16 + ((kc^s2)<<6)
  //   s_a=(col^(col>>1))&7, s2=s_a>>2, qa=quad^(s_a&3).
  // mt term (mt*8192) folds into the ds_read immediate offset.
  const int s_a = (col ^ (col >> 1)) & 7;
  const int s2  = (s_a >> 2) & 1;
  const int abase = col * 512 + (quad ^ (s_a & 3)) * 16;
  const char* const hsb = (const char*)hs;

  // One dense layer: D(64x256) = A(64xK) * B(Kx256); A = alpha*h (fp16, LDS),
  // B = fp16 weights (pre-permuted fragments, L2-resident).
  auto run_layer = [&](auto kc_const, const _Float16* __restrict__ wbase,
                       const float* __restrict__ bias_ptr) {
    constexpr int KCOUNT = decltype(kc_const)::value;
    const floatx4 zv = {0.f, 0.f, 0.f, 0.f};
    #pragma unroll
    for (int mt = 0; mt < 4; ++mt)
      #pragma unroll
      for (int nl = 0; nl < 4; ++nl)
        acc[mt][nl] = zv;

    const _Float16* wlane = wbase + wave * 4 * WNC_ELEMS + lane * 8;

    #pragma clang loop unroll(disable)               // keep VGPR pressure flat (<=128)
    for (int kc = 0; kc < KCOUNT; ++kc) {
      half8 b[4];
      const _Float16* wk = wlane + kc * WKC_ELEMS;
      #pragma unroll
      for (int nl = 0; nl < 4; ++nl)
        b[nl] = *(const half8*)(wk + nl * WNC_ELEMS);
      half8 a[4];
      const char* ap = hsb + abase + ((kc ^ s2) << 6);
      #pragma unroll
      for (int mt = 0; mt < 4; ++mt)
        a[mt] = *(const half8*)(ap + mt * 8192);     // imm-offset ds_read_b128
      __builtin_amdgcn_s_setprio(1);
      #pragma unroll
      for (int nl = 0; nl < 4; ++nl)
        #pragma unroll
        for (int mt = 0; mt < 4; ++mt)
          acc[mt][nl] = __builtin_amdgcn_mfma_f32_16x16x32_f16(a[mt], b[nl], acc[mt][nl], 0, 0, 0);
      __builtin_amdgcn_s_setprio(0);
    }
    __syncthreads();   // all waves done reading hs before overwrite

    // R13 epilogue address strength reduction. Write target (m,n):
    //   m = mt*16 + quad*4 + r, n = wave*64 + nl*16 + col.
    //   byte = mt*8192 (ds imm) + (quad*4+r)*512 + wave*128
    //        + ((v^s_r)<<4) + (col&7)*2,  v = nl*2|c3, s_r=(m0^(m0>>1))&7.
    {
      const int c3   = (col >> 3) & 1;
      const int ebase = wave * 128 + ((col & 7) << 1);
      #pragma unroll
      for (int nl = 0; nl < 4; ++nl) {
        int n = wave * 64 + nl * 16 + col;
        float biasA = bias_ptr[n] * ALPHA;           // bias scaled by alpha
        #pragma unroll
        for (int r = 0; r < 4; ++r) {
          int m0  = quad * 4 + r;
          int s_r = (m0 ^ (m0 >> 1)) & 7;
          int va  = m0 * 512 + ebase + (((((nl << 1) | c3)) ^ s_r) << 4);
          char* wp = (char*)hs + va;
          #pragma unroll
          for (int mt = 0; mt < 4; ++mt) {
            float hv = fmaxf(acc[mt][nl][r] + biasA, 0.f);   // ReLU pre-next-matmul
            *(_Float16*)(wp + mt * 8192) = (_Float16)hv;     // imm-offset ds_write_b16
          }
        }
      }
    }
    __syncthreads();
  };

  run_layer(std::integral_constant<int, 1>{}, wsh, b_in);
  #pragma clang loop unroll(disable)
  for (int L = 0; L < NMID; ++L)
    run_layer(std::integral_constant<int, 8>{}, wsh + WIN_ELEMS + L * WL_ELEMS, b_mid + L * DIM);

  // ---------------- output layer: out = (alpha*relu h).W_out / alpha + b_out ----
  // R9 vectorized epilogue; R18: W_out from LDS stage (imm-offset ds_read_b128).
  {
    int m = tid >> 2, seg = tid & 3;          // same-m threads adjacent -> shuffle reduce
    float sum = 0.f;
    #pragma unroll
    for (int i = 0; i < 8; ++i) {
      int k = (seg << 6) + (i << 3);          // 8-aligned group within this thread's 64-wide segment
      half8 hv = *(const half8*)&hs[sw_idx(m, k)];
      float4 w0 = *(const float4*)&wout_s[k];
      float4 w1 = *(const float4*)&wout_s[k + 4];
      sum += (float)hv[0] * w0.x + (float)hv[1] * w0.y
           + (float)hv[2] * w0.z + (float)hv[3] * w0.w
           + (float)hv[4] * w1.x + (float)hv[5] * w1.y
           + (float)hv[6] * w1.z + (float)hv[7] * w1.w;
    }
    sum += __shfl_xor(sum, 1);
    sum += __shfl_xor(sum, 2);
    if (seg == 0) out[rbase + m] = sum * INV_ALPHA + b_out[0];
  }
}

extern "C" void kernel_launch(void* const* d_in, const int* in_sizes, int n_in,
                              void* d_out, int out_size, void* d_ws, size_t ws_size,
                              hipStream_t stream)
{
  const float* x      = (const float*)d_in[0];
  const float* table1 = (const float*)d_in[1];
  const float* table2 = (const float*)d_in[2];
  const float* W_in   = (const float*)d_in[3];
  const float* b_in   = (const float*)d_in[4];
  const float* W_mid  = (const float*)d_in[5];
  const float* b_mid  = (const float*)d_in[6];
  const float* W_out  = (const float*)d_in[7];
  const float* b_out  = (const float*)d_in[8];
  float* out  = (float*)d_out;
  _Float16* wsh = (_Float16*)d_ws;

  // Resolutions: identical double-precision op sequence as the Python module (same libm).
  double b = exp((log(512.0) - log(16.0)) / 3.0);
  int res[4];
  for (int l = 0; l < 4; ++l) res[l] = (int)floor(16.0 * pow(b, (double)l));

  int prep_total = WIN_ELEMS + 6 * WL_ELEMS;   // 401408 = 1568 * 256
  prep_weights<<<prep_total / 256, 256, 0, stream>>>(W_in, W_mid, wsh);
  mlp_fused<<<NRAYS / MBLK, 256, 0, stream>>>(x, table1, table2, wsh, b_in, b_mid,
                                              W_out, b_out, out,
                                              res[0], res[1], res[2], res[3]);
}